// Round 1
// baseline (240.803 us; speedup 1.0000x reference)
//
#include <hip/hip_runtime.h>

// Depthwise 5x5 box blur, zero 'same' padding.
// x: (16, 8, 512, 512) fp32 -> out: same shape.
// Separable (5x1 then 1x5) fused in one kernel via LDS tile.

#define H 512
#define W 512
#define TH 16               // output rows per block
#define LROWS (TH + 4)      // 20 staged rows (2-halo each side)
#define LSTRIDE (W + 8)     // 520 floats: 4 left pad (aligned), data at +4, right pad
// data col x lives at LDS col x+4; window x-2..x+2 -> LDS cols x+2..x+6

__global__ __launch_bounds__(256) void avefilter_kernel(
    const float* __restrict__ x, const float* __restrict__ wgt,
    float* __restrict__ out) {
    __shared__ float smem[LROWS * LSTRIDE];  // 41600 B

    const int tid   = threadIdx.x;
    const int r0    = blockIdx.x * TH;      // first output row of this tile
    const int plane = blockIdx.y;           // n*C + c, 0..127

    const float* in   = x   + (size_t)plane * (H * W);
    float*       outp = out + (size_t)plane * (H * W);
    const float scale = wgt[0];             // == 1/25 (uniform kernel)

    // Zero the 8 pad columns (0..3 and 516..519) for all 20 rows: 160 elems.
    for (int i = tid; i < LROWS * 8; i += 256) {
        int lr = i >> 3;
        int c  = i & 7;
        int lc = (c < 4) ? c : (W + c);     // 0..3 or 516..519
        smem[lr * LSTRIDE + lc] = 0.0f;
    }

    // Stage 20 rows x 512 cols as float4 (zero rows outside the plane).
    // 20 * 128 = 2560 float4 ops; 10 per thread, fully coalesced.
    for (int i = tid; i < LROWS * (W / 4); i += 256) {
        int lr = i >> 7;          // i / 128
        int vc = i & 127;         // i % 128
        int gr = r0 - 2 + lr;
        float4 v = make_float4(0.f, 0.f, 0.f, 0.f);
        if (gr >= 0 && gr < H) {
            v = ((const float4*)(in + (size_t)gr * W))[vc];
        }
        ((float4*)(smem + lr * LSTRIDE + 4))[vc] = v;  // +4 floats = 16B aligned
    }
    __syncthreads();

    // Each thread: columns tid and tid+256, 16 output rows each.
    // Horizontal 5-sums from LDS (consecutive lanes -> consecutive addrs,
    // 2-way bank aliasing = free), vertical slide in registers.
    #pragma unroll
    for (int ci = 0; ci < 2; ++ci) {
        const int xcol = tid + ci * 256;
        const float* bcol = smem + xcol + 2;   // hsum window base

        float h[5];
        #pragma unroll
        for (int i = 0; i < 5; ++i) {
            const float* b = bcol + i * LSTRIDE;
            h[i] = b[0] + b[1] + b[2] + b[3] + b[4];
        }

        #pragma unroll
        for (int r = 0; r < TH; ++r) {
            float s = h[0] + h[1] + h[2] + h[3] + h[4];
            outp[(size_t)(r0 + r) * W + xcol] = s * scale;
            if (r < TH - 1) {
                const float* b = bcol + (r + 5) * LSTRIDE;
                h[r % 5] = b[0] + b[1] + b[2] + b[3] + b[4];
            }
        }
    }
}

extern "C" void kernel_launch(void* const* d_in, const int* in_sizes, int n_in,
                              void* d_out, int out_size, void* d_ws, size_t ws_size,
                              hipStream_t stream) {
    const float* x   = (const float*)d_in[0];
    const float* wgt = (const float*)d_in[1];
    float* out = (float*)d_out;

    dim3 grid(H / TH, 16 * 8);   // 32 row-tiles x 128 planes = 4096 blocks
    dim3 block(256);
    avefilter_kernel<<<grid, block, 0, stream>>>(x, wgt, out);
}